// Round 13
// baseline (542.342 us; speedup 1.0000x reference)
//
#include <hip/hip_runtime.h>

#define SEQ 64
#define LOG2E 1.4426950408889634f

typedef _Float16 f16;
typedef _Float16 f16x8 __attribute__((ext_vector_type(8)));
typedef _Float16 f16x2 __attribute__((ext_vector_type(2)));
typedef float f32x4 __attribute__((ext_vector_type(4)));

__device__ __forceinline__ float exp2_(float x) {
#if __has_builtin(__builtin_amdgcn_exp2f)
  return __builtin_amdgcn_exp2f(x);
#else
  return __builtin_exp2f(x);
#endif
}
// gates on pre-scaled accumulators: a = log2e*x (sig), a = 2*log2e*x (tanh-g)
__device__ __forceinline__ float sigp_(float a) {
  return __builtin_amdgcn_rcpf(1.0f + exp2_(-a));
}
__device__ __forceinline__ float tanhp_(float a) {
  return 1.0f - 2.0f * __builtin_amdgcn_rcpf(1.0f + exp2_(a));
}
__device__ __forceinline__ float tanh_(float x) {   // true-scale input
  return 1.0f - 2.0f * __builtin_amdgcn_rcpf(1.0f + exp2_(x * (2.0f * LOG2E)));
}

template<int CTRL, int RMASK>
__device__ __forceinline__ float dpp_add(float x) {
  const int t = __builtin_amdgcn_update_dpp(0, __float_as_int(x), CTRL, RMASK, 0xF, true);
  return x + __int_as_float(t);
}
template<int CTRL>
__device__ __forceinline__ float dpp_max(float x) {
  const int t = __builtin_amdgcn_update_dpp(0, __float_as_int(x), CTRL, 0xF, 0xF, true);
  return fmaxf(x, __int_as_float(t));
}
__device__ __forceinline__ float red16(float v) {   // sum over 16-lane row
  v = dpp_add<0xB1, 0xF>(v);
  v = dpp_add<0x4E, 0xF>(v);
  v = dpp_add<0x124, 0xF>(v);
  v = dpp_add<0x128, 0xF>(v);
  return v;
}
__device__ __forceinline__ float lane63f(float v) { // uniform broadcast of lane 63
  return __int_as_float(__builtin_amdgcn_readlane(__float_as_int(v), 63));
}

// h state: node-major, UNSWIZZLED, row stride 136 f16 (272 B).
#define HROW 136

// gather one MFMA B-fragment set (kk, q), scaled by sc (exp2 pre-scaling)
__device__ __forceinline__ f16x8 gatherB(const float* __restrict__ cW,
                                         int kk, int q, int wv, int quad, int l15,
                                         float sc) {
  const int col = (q * 8 + wv) * 16 + l15;
  const int kb  = kk * 32 + quad * 8;
  f16x8 v;
  #pragma unroll
  for (int j = 0; j < 8; ++j) v[j] = (f16)(cW[(kb + j) * 640 + col] * sc);
  return v;
}

// Dynamic-LDS partition (149.5 KiB total; 1 block/CU, 160 KiB available)
#define BLDS_OFF 0              // 12 B-frag sets: 12*512*16 = 98304
#define CS_OFF   98304          // c state f32: 65*132*4 = 34320
#define HS_OFF   132624         // h state f16: 65*136*2 = 17680
#define LGP_OFF  150304         // logit partials: 8*64*4 = 2048
#define PS_OFF   152352         // p: 64*4
#define CLS_OFF  152608         // copy_left: 64*4
#define CRS_OFF  152864         // copy_right: 64*4
#define DYN_LDS  153120

// ---- pyramid (+ fused z0): 512 threads, 64 blocks (1 per CU) ----
// R13: reverted R11's z1 fusion (w1 per-block duplication cost +68us vs the
// column-split z1 kernel's ~26us — column reuse across batch wins). Single
// new tweak vs the 434.3us baseline: per-LAYER hoist of the mt-invariant
// Blds fragments (b3 kk>=4, b4 all kk) into registers b3L/b4L — the same 12
// b128 values were re-read per mt (up to 4x/layer). Saves ~18 b128/thread/
// layer on the saturated LDS pipe. B-operands can live in AGPRs (unified
// file), same as Breg.
__global__ __launch_bounds__(512, 1) void pyramid_kernel(
    const int*   __restrict__ sentences,
    const float* __restrict__ emb,
    const float* __restrict__ cW,
    const float* __restrict__ cb, const float* __restrict__ selw, const float* __restrict__ selb,
    const float* __restrict__ w0, const float* __restrict__ b0,
    const float* __restrict__ cbias,
    f16* __restrict__ z0h, float* __restrict__ out)
{
  extern __shared__ __align__(16) char dyn[];
  f16x8* Blds = (f16x8*)(dyn + BLDS_OFF);
  float* cS   = (float*)(dyn + CS_OFF);
  f16*   hS   = (f16*)  (dyn + HS_OFF);
  float* lgp  = (float*)(dyn + LGP_OFF);
  float* pS   = (float*)(dyn + PS_OFF);
  float* clS  = (float*)(dyn + CLS_OFF);
  float* crS  = (float*)(dyn + CRS_OFF);

  const int tid  = threadIdx.x;
  const int b    = blockIdx.x;
  const int wv   = tid >> 6;
  const int lane = tid & 63;
  const int quad = lane >> 4;
  const int l15  = lane & 15;
  const int d    = wv * 16 + l15;

  // init logits with cbias (z1 kernel atomically accumulates onto this)
  if (b == 0 && tid < 192) out[tid] = cbias[tid % 3];

  // ---- B in LDS: s<4 -> (kk=4+s, q=3); s>=4 -> (kk=s-4, q=4) ----
  #pragma unroll
  for (int s = 0; s < 12; ++s) {
    const int kk = (s < 4) ? (4 + s) : (s - 4);
    const int q  = (s < 4) ? 3 : 4;
    const float sc = (q == 3) ? (2.0f * LOG2E) : LOG2E;
    Blds[s * 512 + tid] = gatherB(cW, kk, q, wv, quad, l15, sc);
  }
  // ---- persistent B in regs: q=0..2 all kk (24) + q=3,kk=0..3 (4) = 28 sets ----
  f16x8 Breg[28];
  #pragma unroll
  for (int kk = 0; kk < 8; ++kk)
    #pragma unroll
    for (int q = 0; q < 3; ++q)
      Breg[kk * 3 + q] = gatherB(cW, kk, q, wv, quad, l15, LOG2E);
  #pragma unroll
  for (int kk = 0; kk < 4; ++kk)
    Breg[24 + kk] = gatherB(cW, kk, 3, wv, quad, l15, 2.0f * LOG2E);

  // ---- embedding gather: h -> LDS f16, c -> LDS f32 ----
  {
    const int s = tid >> 3, part = tid & 7;
    const int row = sentences[b * SEQ + s];
    const float4* er = (const float4*)(emb + (size_t)row * 256 + part * 32);
    #pragma unroll
    for (int i4 = 0; i4 < 8; ++i4) {
      const float4 v = er[i4];
      const float vv[4] = {v.x, v.y, v.z, v.w};
      #pragma unroll
      for (int c = 0; c < 4; ++c) {
        const int f = part * 32 + i4 * 4 + c;
        if (f < 128) hS[s * HROW + f] = (f16)vv[c];
        else         cS[s * 132 + (f - 128)] = vv[c];
      }
    }
  }
  if (tid < HROW) hS[64 * HROW + tid] = (f16)0.f;   // guard row (node 64)
  if (tid < 132)  cS[64 * 132 + tid] = 0.f;
  __syncthreads();

  float bq[5];
  #pragma unroll
  for (int q = 0; q < 5; ++q)
    bq[q] = cb[q * 128 + d] * ((q == 3) ? (2.0f * LOG2E) : LOG2E);
  const float swh = selw[d], swc = selw[128 + d], selbv = selb[0];

  // ---- pyramid: 63 sequential layers; zero global memory in the loop ----
  for (int W = 63; W >= 1; --W) {
    const int NMT = (W + 15) >> 4;
    float chF[4][4], ccF[4][4], vF[4][4];

    // per-layer hoist of mt-invariant Blds fragments (12 b128 reads, once)
    f16x8 b3L[4], b4L[8];
    #pragma unroll
    for (int kk = 4; kk < 8; ++kk) b3L[kk - 4] = Blds[(kk - 4) * 512 + tid];
    #pragma unroll
    for (int kk = 0; kk < 8; ++kk) b4L[kk] = Blds[(4 + kk) * 512 + tid];

    // ---- phase A: MFMA + gate epilogue, one mt at a time (NO LDS writes) ----
    #pragma unroll
    for (int mt = 0; mt < 4; ++mt) if (mt < NMT) {
      f32x4 acc[5];
      #pragma unroll
      for (int q = 0; q < 5; ++q) acc[q] = (f32x4){bq[q], bq[q], bq[q], bq[q]};
      const int rb = (mt * 16 + l15) * HROW + quad * 8;   // layer-invariant base
      #pragma unroll
      for (int kk = 0; kk < 8; ++kk) {
        const f16x8 av = *(const f16x8*)&hS[rb + (kk >> 2) * HROW + (kk & 3) * 32];
        #pragma unroll
        for (int q = 0; q < 3; ++q)
          acc[q] = __builtin_amdgcn_mfma_f32_16x16x32_f16(av, Breg[kk * 3 + q], acc[q], 0, 0, 0);
        const f16x8 b3 = (kk < 4) ? Breg[24 + kk] : b3L[kk - 4];
        acc[3] = __builtin_amdgcn_mfma_f32_16x16x32_f16(av, b3, acc[3], 0, 0, 0);
        acc[4] = __builtin_amdgcn_mfma_f32_16x16x32_f16(av, b4L[kk], acc[4], 0, 0, 0);
      }
      const int n0q = mt * 16 + quad * 4;
      if (n0q < W) {                    // quad-uniform: whole dead quads skip
        float c5[5];
        #pragma unroll
        for (int r = 0; r < 5; ++r) c5[r] = cS[(n0q + r) * 132 + d];
        #pragma unroll
        for (int r = 0; r < 4; ++r) {
          const float c = sigp_(acc[1][r]) * c5[r] + sigp_(acc[2][r]) * c5[r + 1]
                        + sigp_(acc[0][r]) * tanhp_(acc[3][r]);
          const float h = sigp_(acc[4][r]) * tanh_(c);
          ccF[mt][r] = c; chF[mt][r] = h;
          vF[mt][r] = red16(__builtin_fmaf(h, swh, c * swc));   // logit partial
        }
      }
    }
    // ---- flush logit partials (single LDS-write block, after all reads) ----
    if (l15 == 0) {
      #pragma unroll
      for (int mt = 0; mt < 4; ++mt) if (mt < NMT) {
        const int n0q = mt * 16 + quad * 4;
        if (n0q < W) {
          #pragma unroll
          for (int r = 0; r < 4; ++r) {
            const int n = n0q + r;
            if (n < W) lgp[(wv << 6) + n] = vF[mt][r];
          }
        }
      }
    }
    __syncthreads();

    // ---- phase B: softmax + prefix sums, redundantly per wave ----
    {
      float lg = -3.0e38f;
      if (lane < W) {
        float s = selbv;
        #pragma unroll
        for (int dg = 0; dg < 8; ++dg) s += lgp[(dg << 6) + lane];
        lg = s;
      }
      // full-wave max: row butterfly then row_bcast chain; total lands in lane 63
      float m = lg;
      m = dpp_max<0xB1>(m); m = dpp_max<0x4E>(m);
      m = dpp_max<0x124>(m); m = dpp_max<0x128>(m);
      m = dpp_max<0x142>(m); m = dpp_max<0x143>(m);
      m = lane63f(m);
      const float e = (lane < W) ? __expf(lg - m) : 0.f;
      float t = e;
      t = dpp_add<0xB1, 0xF>(t); t = dpp_add<0x4E, 0xF>(t);
      t = dpp_add<0x124, 0xF>(t); t = dpp_add<0x128, 0xF>(t);
      t = dpp_add<0x142, 0xF>(t); t = dpp_add<0x143, 0xF>(t);
      t = lane63f(t);
      const float p = e * __builtin_amdgcn_rcpf(t);
      float cs = p;                       // inclusive scan (DPP)
      cs = dpp_add<0x111, 0xF>(cs);
      cs = dpp_add<0x112, 0xF>(cs);
      cs = dpp_add<0x114, 0xF>(cs);
      cs = dpp_add<0x118, 0xF>(cs);
      cs = dpp_add<0x142, 0xA>(cs);
      cs = dpp_add<0x143, 0xC>(cs);
      const float T = lane63f(cs);
      if (lane < W) {
        pS[lane]  = p;
        clS[lane] = T - cs;
        crS[lane] = cs - p;
      }
    }
    // (no barrier: each wave wrote its own redundant copy)

    // ---- phase C: blend; read-all-then-write-all per mt ----
    #pragma unroll
    for (int mt = 0; mt < 4; ++mt) if (mt < NMT) {
      const int n0q = mt * 16 + quad * 4;
      if (n0q < W) {                    // skip dead quads entirely
        const f32x4 pv  = *(const f32x4*)&pS[n0q];
        const f32x4 clv = *(const f32x4*)&clS[n0q];
        const f32x4 crv = *(const f32x4*)&crS[n0q];
        float oh[5], c5[5];
        #pragma unroll
        for (int r = 0; r < 5; ++r) {
          oh[r] = (float)hS[(n0q + r) * HROW + d];
          c5[r] = cS[(n0q + r) * 132 + d];
        }
        #pragma unroll
        for (int r = 0; r < 4; ++r) {
          const int n = n0q + r;
          if (n < W) {
            const float nh = clv[r] * oh[r] + crv[r] * oh[r + 1] + pv[r] * chF[mt][r];
            const float nc = clv[r] * c5[r] + crv[r] * c5[r + 1] + pv[r] * ccF[mt][r];
            hS[n * HROW + d] = (f16)nh;
            cS[n * 132 + d] = nc;
          }
        }
      }
    }
    __syncthreads();
  }

  // ---- fused z0: x = [h0||c0] (in LDS); each thread 2 cols; output f16 ----
  {
    const int c0 = 2 * tid;
    float a0 = 0.f, a1 = 0.f;
    #pragma unroll 8
    for (int k = 0; k < 128; ++k) {
      const float x  = (float)hS[k];                       // row 0, LDS broadcast
      const float2 w = *(const float2*)&w0[k * 1024 + c0]; // coalesced
      a0 = __builtin_fmaf(x, w.x, a0);
      a1 = __builtin_fmaf(x, w.y, a1);
    }
    #pragma unroll 8
    for (int k = 0; k < 128; ++k) {
      const float x  = cS[k];                              // LDS broadcast
      const float2 w = *(const float2*)&w0[(128 + k) * 1024 + c0];
      a0 = __builtin_fmaf(x, w.x, a0);
      a1 = __builtin_fmaf(x, w.y, a1);
    }
    f16x2 p;
    p[0] = (f16)fmaxf(a0 + b0[c0], 0.f);
    p[1] = (f16)fmaxf(a1 + b0[c0 + 1], 0.f);
    *(f16x2*)&z0h[b * 1024 + c0] = p;      // z0h[row=b][k], A-operand layout
  }
}

// ---- z1 + classifier, MFMA: 64 blocks x 256 thr (4 waves) ----
// Block = 16 cols of w1 (column-split => w1 read ONCE device-wide).
#define ZROW 264   // 256 + 8 f16 pad (4-bank row stride)
__global__ __launch_bounds__(256) void z1_kernel(
    const f16* __restrict__ z0h, const float* __restrict__ w1,
    const float* __restrict__ b1, const float* __restrict__ cwt,
    float* __restrict__ out)
{
  __shared__ __align__(16) f16 ZL[64 * ZROW];   // 33792 B
  __shared__ __align__(16) f16 WL[16 * ZROW];   // 8448 B
  const int t    = threadIdx.x;
  const int wv   = t >> 6;
  const int lane = t & 63;
  const int quad = lane >> 4;
  const int l15  = lane & 15;
  const int c0   = blockIdx.x * 16;

  f32x4 acc = (f32x4){0.f, 0.f, 0.f, 0.f};
  for (int k0 = 0; k0 < 1024; k0 += 256) {
    __syncthreads();                      // protect previous chunk's reads
    // stage z0h chunk: 64 rows x 256 k (f16), b128 copies
    #pragma unroll
    for (int i = 0; i < 8; ++i) {
      const int idx8 = (t + i * 256) * 8;          // 0..16376
      const int row  = idx8 >> 8;
      const int ko   = idx8 & 255;
      *(f16x8*)&ZL[row * ZROW + ko] = *(const f16x8*)&z0h[row * 1024 + k0 + ko];
    }
    // stage w1 slice transposed: WL[col][k] f16, via coalesced float4 loads
    #pragma unroll
    for (int i = 0; i < 4; ++i) {
      const int idx = i * 256 + t;                  // 0..1023
      const int kc  = idx >> 2;                     // k-row 0..255
      const int c4  = (idx & 3) * 4;                // col group 0,4,8,12
      const float4 w4 = *(const float4*)&w1[(size_t)(k0 + kc) * 1024 + c0 + c4];
      WL[(c4 + 0) * ZROW + kc] = (f16)w4.x;
      WL[(c4 + 1) * ZROW + kc] = (f16)w4.y;
      WL[(c4 + 2) * ZROW + kc] = (f16)w4.z;
      WL[(c4 + 3) * ZROW + kc] = (f16)w4.w;
    }
    __syncthreads();
    #pragma unroll
    for (int kk = 0; kk < 8; ++kk) {
      const f16x8 av = *(const f16x8*)&ZL[(wv * 16 + l15) * ZROW + kk * 32 + quad * 8];
      const f16x8 bv = *(const f16x8*)&WL[l15 * ZROW + kk * 32 + quad * 8];
      acc = __builtin_amdgcn_mfma_f32_16x16x32_f16(av, bv, acc, 0, 0, 0);
    }
  }

  // epilogue: z1 = relu(acc + b1); classifier partials over this block's 16 cols
  const int col = c0 + l15;
  const float bias = b1[col];
  const float cw0 = cwt[col * 3], cw1 = cwt[col * 3 + 1], cw2 = cwt[col * 3 + 2];
  #pragma unroll
  for (int r = 0; r < 4; ++r) {
    const int row = wv * 16 + quad * 4 + r;
    const float z = fmaxf(acc[r] + bias, 0.f);
    const float p0 = red16(z * cw0);
    const float p1 = red16(z * cw1);
    const float p2 = red16(z * cw2);
    if (l15 == 0) {
      atomicAdd(&out[row * 3 + 0], p0);
      atomicAdd(&out[row * 3 + 1], p1);
      atomicAdd(&out[row * 3 + 2], p2);
    }
  }
}

extern "C" void kernel_launch(void* const* d_in, const int* in_sizes, int n_in,
                              void* d_out, int out_size, void* d_ws, size_t ws_size,
                              hipStream_t stream) {
  (void)in_sizes; (void)n_in; (void)out_size; (void)ws_size;
  f16* z0h = (f16*)d_ws;                                 // 64*1024*2 = 131072 B

  // allow >64 KB dynamic LDS (160 KiB/CU on gfx950); host-state call, not enqueued
  (void)hipFuncSetAttribute((const void*)pyramid_kernel,
                            hipFuncAttributeMaxDynamicSharedMemorySize, DYN_LDS);

  pyramid_kernel<<<dim3(64), dim3(512), DYN_LDS, stream>>>(
      (const int*)d_in[0],          // sentences
      (const float*)d_in[2],        // emb
      (const float*)d_in[3],        // comp_W (self-gathered to fragments)
      (const float*)d_in[4],        // comp_b
      (const float*)d_in[5],        // sel_w
      (const float*)d_in[6],        // sel_b
      (const float*)d_in[7],        // mlp_w0
      (const float*)d_in[8],        // mlp_b0
      (const float*)d_in[12],       // cls_b (out init)
      z0h, (float*)d_out);
  z1_kernel<<<dim3(64), dim3(256), 0, stream>>>(
      z0h,
      (const float*)d_in[9],        // mlp_w1
      (const float*)d_in[10],       // mlp_b1
      (const float*)d_in[11],       // cls_w
      (float*)d_out);
}

// Round 14
// 446.161 us; speedup vs baseline: 1.2156x; 1.2156x over previous
//
#include <hip/hip_runtime.h>

#define SEQ 64
#define LOG2E 1.4426950408889634f

typedef _Float16 f16;
typedef _Float16 f16x8 __attribute__((ext_vector_type(8)));
typedef _Float16 f16x2 __attribute__((ext_vector_type(2)));
typedef float f32x4 __attribute__((ext_vector_type(4)));

__device__ __forceinline__ float exp2_(float x) {
#if __has_builtin(__builtin_amdgcn_exp2f)
  return __builtin_amdgcn_exp2f(x);
#else
  return __builtin_exp2f(x);
#endif
}
// gates on pre-scaled accumulators: a = log2e*x (sig), a = 2*log2e*x (tanh-g)
__device__ __forceinline__ float sigp_(float a) {
  return __builtin_amdgcn_rcpf(1.0f + exp2_(-a));
}
__device__ __forceinline__ float tanhp_(float a) {
  return 1.0f - 2.0f * __builtin_amdgcn_rcpf(1.0f + exp2_(a));
}
__device__ __forceinline__ float tanh_(float x) {   // true-scale input
  return 1.0f - 2.0f * __builtin_amdgcn_rcpf(1.0f + exp2_(x * (2.0f * LOG2E)));
}

template<int CTRL, int RMASK>
__device__ __forceinline__ float dpp_add(float x) {
  const int t = __builtin_amdgcn_update_dpp(0, __float_as_int(x), CTRL, RMASK, 0xF, true);
  return x + __int_as_float(t);
}
template<int CTRL>
__device__ __forceinline__ float dpp_max(float x) {
  const int t = __builtin_amdgcn_update_dpp(0, __float_as_int(x), CTRL, 0xF, 0xF, true);
  return fmaxf(x, __int_as_float(t));
}
__device__ __forceinline__ float red16(float v) {   // sum over 16-lane row
  v = dpp_add<0xB1, 0xF>(v);
  v = dpp_add<0x4E, 0xF>(v);
  v = dpp_add<0x124, 0xF>(v);
  v = dpp_add<0x128, 0xF>(v);
  return v;
}
__device__ __forceinline__ float lane63f(float v) { // uniform broadcast of lane 63
  return __int_as_float(__builtin_amdgcn_readlane(__float_as_int(v), 63));
}

// h state: node-major, UNSWIZZLED, row stride 136 f16 (272 B).
#define HROW 136

// gather one MFMA B-fragment set (kk, q), scaled by sc (exp2 pre-scaling)
__device__ __forceinline__ f16x8 gatherB(const float* __restrict__ cW,
                                         int kk, int q, int wv, int quad, int l15,
                                         float sc) {
  const int col = (q * 8 + wv) * 16 + l15;
  const int kb  = kk * 32 + quad * 8;
  f16x8 v;
  #pragma unroll
  for (int j = 0; j < 8; ++j) v[j] = (f16)(cW[(kb + j) * 640 + col] * sc);
  return v;
}

// Dynamic-LDS partition (149.5 KiB total; 1 block/CU, 160 KiB available)
#define BLDS_OFF 0              // 12 B-frag sets: 12*512*16 = 98304
#define CS_OFF   98304          // c state f32: 65*132*4 = 34320
#define HS_OFF   132624         // h state f16: 65*136*2 = 17680
#define LGP_OFF  150304         // logit partials: 8*64*4 = 2048
#define PS_OFF   152352         // p: 64*4
#define CLS_OFF  152608         // copy_left: 64*4
#define CRS_OFF  152864         // copy_right: 64*4
#define DYN_LDS  153120

// ---- pyramid (+ fused z0): 512 threads, 64 blocks (1 per CU) ----
// R14: revert R13's 48-reg hoist (third spill; measured budget = 128 VGPR +
// ~128 AGPR, Breg[28]=112 leaves exactly 16 AGPRs spare). This round hoists
// ONLY b3L[4] (kk>=4 b3 sets, 16 regs = exact fit): per-layer instead of
// per-mt, saving 4 of 12 Blds b128 reads per mt on the saturated LDS pipe.
__global__ __launch_bounds__(512, 1) void pyramid_kernel(
    const int*   __restrict__ sentences,
    const float* __restrict__ emb,
    const float* __restrict__ cW,
    const float* __restrict__ cb, const float* __restrict__ selw, const float* __restrict__ selb,
    const float* __restrict__ w0, const float* __restrict__ b0,
    const float* __restrict__ cbias,
    f16* __restrict__ z0h, float* __restrict__ out)
{
  extern __shared__ __align__(16) char dyn[];
  f16x8* Blds = (f16x8*)(dyn + BLDS_OFF);
  float* cS   = (float*)(dyn + CS_OFF);
  f16*   hS   = (f16*)  (dyn + HS_OFF);
  float* lgp  = (float*)(dyn + LGP_OFF);
  float* pS   = (float*)(dyn + PS_OFF);
  float* clS  = (float*)(dyn + CLS_OFF);
  float* crS  = (float*)(dyn + CRS_OFF);

  const int tid  = threadIdx.x;
  const int b    = blockIdx.x;
  const int wv   = tid >> 6;
  const int lane = tid & 63;
  const int quad = lane >> 4;
  const int l15  = lane & 15;
  const int d    = wv * 16 + l15;

  // init logits with cbias (z1 kernel atomically accumulates onto this)
  if (b == 0 && tid < 192) out[tid] = cbias[tid % 3];

  // ---- B in LDS: s<4 -> (kk=4+s, q=3); s>=4 -> (kk=s-4, q=4) ----
  #pragma unroll
  for (int s = 0; s < 12; ++s) {
    const int kk = (s < 4) ? (4 + s) : (s - 4);
    const int q  = (s < 4) ? 3 : 4;
    const float sc = (q == 3) ? (2.0f * LOG2E) : LOG2E;
    Blds[s * 512 + tid] = gatherB(cW, kk, q, wv, quad, l15, sc);
  }
  // ---- persistent B in regs: q=0..2 all kk (24) + q=3,kk=0..3 (4) = 28 sets ----
  f16x8 Breg[28];
  #pragma unroll
  for (int kk = 0; kk < 8; ++kk)
    #pragma unroll
    for (int q = 0; q < 3; ++q)
      Breg[kk * 3 + q] = gatherB(cW, kk, q, wv, quad, l15, LOG2E);
  #pragma unroll
  for (int kk = 0; kk < 4; ++kk)
    Breg[24 + kk] = gatherB(cW, kk, 3, wv, quad, l15, 2.0f * LOG2E);

  // ---- embedding gather: h -> LDS f16, c -> LDS f32 ----
  {
    const int s = tid >> 3, part = tid & 7;
    const int row = sentences[b * SEQ + s];
    const float4* er = (const float4*)(emb + (size_t)row * 256 + part * 32);
    #pragma unroll
    for (int i4 = 0; i4 < 8; ++i4) {
      const float4 v = er[i4];
      const float vv[4] = {v.x, v.y, v.z, v.w};
      #pragma unroll
      for (int c = 0; c < 4; ++c) {
        const int f = part * 32 + i4 * 4 + c;
        if (f < 128) hS[s * HROW + f] = (f16)vv[c];
        else         cS[s * 132 + (f - 128)] = vv[c];
      }
    }
  }
  if (tid < HROW) hS[64 * HROW + tid] = (f16)0.f;   // guard row (node 64)
  if (tid < 132)  cS[64 * 132 + tid] = 0.f;
  __syncthreads();

  float bq[5];
  #pragma unroll
  for (int q = 0; q < 5; ++q)
    bq[q] = cb[q * 128 + d] * ((q == 3) ? (2.0f * LOG2E) : LOG2E);
  const float swh = selw[d], swc = selw[128 + d], selbv = selb[0];

  // ---- pyramid: 63 sequential layers; zero global memory in the loop ----
  for (int W = 63; W >= 1; --W) {
    const int NMT = (W + 15) >> 4;
    float chF[4][4], ccF[4][4], vF[4][4];

    // per-layer hoist: b3 for kk>=4 only (4 sets = 16 AGPRs, exact spare fit)
    f16x8 b3L[4];
    #pragma unroll
    for (int kk = 4; kk < 8; ++kk) b3L[kk - 4] = Blds[(kk - 4) * 512 + tid];

    // ---- phase A: MFMA + gate epilogue, one mt at a time (NO LDS writes) ----
    #pragma unroll
    for (int mt = 0; mt < 4; ++mt) if (mt < NMT) {
      f32x4 acc[5];
      #pragma unroll
      for (int q = 0; q < 5; ++q) acc[q] = (f32x4){bq[q], bq[q], bq[q], bq[q]};
      const int rb = (mt * 16 + l15) * HROW + quad * 8;   // layer-invariant base
      #pragma unroll
      for (int kk = 0; kk < 8; ++kk) {
        const f16x8 av = *(const f16x8*)&hS[rb + (kk >> 2) * HROW + (kk & 3) * 32];
        #pragma unroll
        for (int q = 0; q < 3; ++q)
          acc[q] = __builtin_amdgcn_mfma_f32_16x16x32_f16(av, Breg[kk * 3 + q], acc[q], 0, 0, 0);
        const f16x8 b3 = (kk < 4) ? Breg[24 + kk] : b3L[kk - 4];
        acc[3] = __builtin_amdgcn_mfma_f32_16x16x32_f16(av, b3, acc[3], 0, 0, 0);
        const f16x8 b4 = Blds[(4 + kk) * 512 + tid];
        acc[4] = __builtin_amdgcn_mfma_f32_16x16x32_f16(av, b4, acc[4], 0, 0, 0);
      }
      const int n0q = mt * 16 + quad * 4;
      if (n0q < W) {                    // quad-uniform: whole dead quads skip
        float c5[5];
        #pragma unroll
        for (int r = 0; r < 5; ++r) c5[r] = cS[(n0q + r) * 132 + d];
        #pragma unroll
        for (int r = 0; r < 4; ++r) {
          const float c = sigp_(acc[1][r]) * c5[r] + sigp_(acc[2][r]) * c5[r + 1]
                        + sigp_(acc[0][r]) * tanhp_(acc[3][r]);
          const float h = sigp_(acc[4][r]) * tanh_(c);
          ccF[mt][r] = c; chF[mt][r] = h;
          vF[mt][r] = red16(__builtin_fmaf(h, swh, c * swc));   // logit partial
        }
      }
    }
    // ---- flush logit partials (single LDS-write block, after all reads) ----
    if (l15 == 0) {
      #pragma unroll
      for (int mt = 0; mt < 4; ++mt) if (mt < NMT) {
        const int n0q = mt * 16 + quad * 4;
        if (n0q < W) {
          #pragma unroll
          for (int r = 0; r < 4; ++r) {
            const int n = n0q + r;
            if (n < W) lgp[(wv << 6) + n] = vF[mt][r];
          }
        }
      }
    }
    __syncthreads();

    // ---- phase B: softmax + prefix sums, redundantly per wave ----
    {
      float lg = -3.0e38f;
      if (lane < W) {
        float s = selbv;
        #pragma unroll
        for (int dg = 0; dg < 8; ++dg) s += lgp[(dg << 6) + lane];
        lg = s;
      }
      // full-wave max: row butterfly then row_bcast chain; total lands in lane 63
      float m = lg;
      m = dpp_max<0xB1>(m); m = dpp_max<0x4E>(m);
      m = dpp_max<0x124>(m); m = dpp_max<0x128>(m);
      m = dpp_max<0x142>(m); m = dpp_max<0x143>(m);
      m = lane63f(m);
      const float e = (lane < W) ? __expf(lg - m) : 0.f;
      float t = e;
      t = dpp_add<0xB1, 0xF>(t); t = dpp_add<0x4E, 0xF>(t);
      t = dpp_add<0x124, 0xF>(t); t = dpp_add<0x128, 0xF>(t);
      t = dpp_add<0x142, 0xF>(t); t = dpp_add<0x143, 0xF>(t);
      t = lane63f(t);
      const float p = e * __builtin_amdgcn_rcpf(t);
      float cs = p;                       // inclusive scan (DPP)
      cs = dpp_add<0x111, 0xF>(cs);
      cs = dpp_add<0x112, 0xF>(cs);
      cs = dpp_add<0x114, 0xF>(cs);
      cs = dpp_add<0x118, 0xF>(cs);
      cs = dpp_add<0x142, 0xA>(cs);
      cs = dpp_add<0x143, 0xC>(cs);
      const float T = lane63f(cs);
      if (lane < W) {
        pS[lane]  = p;
        clS[lane] = T - cs;
        crS[lane] = cs - p;
      }
    }
    // (no barrier: each wave wrote its own redundant copy)

    // ---- phase C: blend; read-all-then-write-all per mt ----
    #pragma unroll
    for (int mt = 0; mt < 4; ++mt) if (mt < NMT) {
      const int n0q = mt * 16 + quad * 4;
      if (n0q < W) {                    // skip dead quads entirely
        const f32x4 pv  = *(const f32x4*)&pS[n0q];
        const f32x4 clv = *(const f32x4*)&clS[n0q];
        const f32x4 crv = *(const f32x4*)&crS[n0q];
        float oh[5], c5[5];
        #pragma unroll
        for (int r = 0; r < 5; ++r) {
          oh[r] = (float)hS[(n0q + r) * HROW + d];
          c5[r] = cS[(n0q + r) * 132 + d];
        }
        #pragma unroll
        for (int r = 0; r < 4; ++r) {
          const int n = n0q + r;
          if (n < W) {
            const float nh = clv[r] * oh[r] + crv[r] * oh[r + 1] + pv[r] * chF[mt][r];
            const float nc = clv[r] * c5[r] + crv[r] * c5[r + 1] + pv[r] * ccF[mt][r];
            hS[n * HROW + d] = (f16)nh;
            cS[n * 132 + d] = nc;
          }
        }
      }
    }
    __syncthreads();
  }

  // ---- fused z0: x = [h0||c0] (in LDS); each thread 2 cols; output f16 ----
  {
    const int c0 = 2 * tid;
    float a0 = 0.f, a1 = 0.f;
    #pragma unroll 8
    for (int k = 0; k < 128; ++k) {
      const float x  = (float)hS[k];                       // row 0, LDS broadcast
      const float2 w = *(const float2*)&w0[k * 1024 + c0]; // coalesced
      a0 = __builtin_fmaf(x, w.x, a0);
      a1 = __builtin_fmaf(x, w.y, a1);
    }
    #pragma unroll 8
    for (int k = 0; k < 128; ++k) {
      const float x  = cS[k];                              // LDS broadcast
      const float2 w = *(const float2*)&w0[(128 + k) * 1024 + c0];
      a0 = __builtin_fmaf(x, w.x, a0);
      a1 = __builtin_fmaf(x, w.y, a1);
    }
    f16x2 p;
    p[0] = (f16)fmaxf(a0 + b0[c0], 0.f);
    p[1] = (f16)fmaxf(a1 + b0[c0 + 1], 0.f);
    *(f16x2*)&z0h[b * 1024 + c0] = p;      // z0h[row=b][k], A-operand layout
  }
}

// ---- z1 + classifier, MFMA: 64 blocks x 256 thr (4 waves) ----
// Block = 16 cols of w1 (column-split => w1 read ONCE device-wide).
#define ZROW 264   // 256 + 8 f16 pad (4-bank row stride)
__global__ __launch_bounds__(256) void z1_kernel(
    const f16* __restrict__ z0h, const float* __restrict__ w1,
    const float* __restrict__ b1, const float* __restrict__ cwt,
    float* __restrict__ out)
{
  __shared__ __align__(16) f16 ZL[64 * ZROW];   // 33792 B
  __shared__ __align__(16) f16 WL[16 * ZROW];   // 8448 B
  const int t    = threadIdx.x;
  const int wv   = t >> 6;
  const int lane = t & 63;
  const int quad = lane >> 4;
  const int l15  = lane & 15;
  const int c0   = blockIdx.x * 16;

  f32x4 acc = (f32x4){0.f, 0.f, 0.f, 0.f};
  for (int k0 = 0; k0 < 1024; k0 += 256) {
    __syncthreads();                      // protect previous chunk's reads
    // stage z0h chunk: 64 rows x 256 k (f16), b128 copies
    #pragma unroll
    for (int i = 0; i < 8; ++i) {
      const int idx8 = (t + i * 256) * 8;          // 0..16376
      const int row  = idx8 >> 8;
      const int ko   = idx8 & 255;
      *(f16x8*)&ZL[row * ZROW + ko] = *(const f16x8*)&z0h[row * 1024 + k0 + ko];
    }
    // stage w1 slice transposed: WL[col][k] f16, via coalesced float4 loads
    #pragma unroll
    for (int i = 0; i < 4; ++i) {
      const int idx = i * 256 + t;                  // 0..1023
      const int kc  = idx >> 2;                     // k-row 0..255
      const int c4  = (idx & 3) * 4;                // col group 0,4,8,12
      const float4 w4 = *(const float4*)&w1[(size_t)(k0 + kc) * 1024 + c0 + c4];
      WL[(c4 + 0) * ZROW + kc] = (f16)w4.x;
      WL[(c4 + 1) * ZROW + kc] = (f16)w4.y;
      WL[(c4 + 2) * ZROW + kc] = (f16)w4.z;
      WL[(c4 + 3) * ZROW + kc] = (f16)w4.w;
    }
    __syncthreads();
    #pragma unroll
    for (int kk = 0; kk < 8; ++kk) {
      const f16x8 av = *(const f16x8*)&ZL[(wv * 16 + l15) * ZROW + kk * 32 + quad * 8];
      const f16x8 bv = *(const f16x8*)&WL[l15 * ZROW + kk * 32 + quad * 8];
      acc = __builtin_amdgcn_mfma_f32_16x16x32_f16(av, bv, acc, 0, 0, 0);
    }
  }

  // epilogue: z1 = relu(acc + b1); classifier partials over this block's 16 cols
  const int col = c0 + l15;
  const float bias = b1[col];
  const float cw0 = cwt[col * 3], cw1 = cwt[col * 3 + 1], cw2 = cwt[col * 3 + 2];
  #pragma unroll
  for (int r = 0; r < 4; ++r) {
    const int row = wv * 16 + quad * 4 + r;
    const float z = fmaxf(acc[r] + bias, 0.f);
    const float p0 = red16(z * cw0);
    const float p1 = red16(z * cw1);
    const float p2 = red16(z * cw2);
    if (l15 == 0) {
      atomicAdd(&out[row * 3 + 0], p0);
      atomicAdd(&out[row * 3 + 1], p1);
      atomicAdd(&out[row * 3 + 2], p2);
    }
  }
}

extern "C" void kernel_launch(void* const* d_in, const int* in_sizes, int n_in,
                              void* d_out, int out_size, void* d_ws, size_t ws_size,
                              hipStream_t stream) {
  (void)in_sizes; (void)n_in; (void)out_size; (void)ws_size;
  f16* z0h = (f16*)d_ws;                                 // 64*1024*2 = 131072 B

  // allow >64 KB dynamic LDS (160 KiB/CU on gfx950); host-state call, not enqueued
  (void)hipFuncSetAttribute((const void*)pyramid_kernel,
                            hipFuncAttributeMaxDynamicSharedMemorySize, DYN_LDS);

  pyramid_kernel<<<dim3(64), dim3(512), DYN_LDS, stream>>>(
      (const int*)d_in[0],          // sentences
      (const float*)d_in[2],        // emb
      (const float*)d_in[3],        // comp_W (self-gathered to fragments)
      (const float*)d_in[4],        // comp_b
      (const float*)d_in[5],        // sel_w
      (const float*)d_in[6],        // sel_b
      (const float*)d_in[7],        // mlp_w0
      (const float*)d_in[8],        // mlp_b0
      (const float*)d_in[12],       // cls_b (out init)
      z0h, (float*)d_out);
  z1_kernel<<<dim3(64), dim3(256), 0, stream>>>(
      z0h,
      (const float*)d_in[9],        // mlp_w1
      (const float*)d_in[10],       // mlp_b1
      (const float*)d_in[11],       // cls_w
      (float*)d_out);
}

// Round 15
// 433.443 us; speedup vs baseline: 1.2512x; 1.0293x over previous
//
#include <hip/hip_runtime.h>

#define SEQ 64
#define LOG2E 1.4426950408889634f

typedef _Float16 f16;
typedef _Float16 f16x8 __attribute__((ext_vector_type(8)));
typedef _Float16 f16x2 __attribute__((ext_vector_type(2)));
typedef float f32x4 __attribute__((ext_vector_type(4)));

__device__ __forceinline__ float exp2_(float x) {
#if __has_builtin(__builtin_amdgcn_exp2f)
  return __builtin_amdgcn_exp2f(x);
#else
  return __builtin_exp2f(x);
#endif
}
// gates on pre-scaled accumulators: a = log2e*x (sig), a = 2*log2e*x (tanh-g)
__device__ __forceinline__ float sigp_(float a) {
  return __builtin_amdgcn_rcpf(1.0f + exp2_(-a));
}
__device__ __forceinline__ float tanhp_(float a) {
  return 1.0f - 2.0f * __builtin_amdgcn_rcpf(1.0f + exp2_(a));
}
__device__ __forceinline__ float tanh_(float x) {   // true-scale input
  return 1.0f - 2.0f * __builtin_amdgcn_rcpf(1.0f + exp2_(x * (2.0f * LOG2E)));
}

template<int CTRL, int RMASK>
__device__ __forceinline__ float dpp_add(float x) {
  const int t = __builtin_amdgcn_update_dpp(0, __float_as_int(x), CTRL, RMASK, 0xF, true);
  return x + __int_as_float(t);
}
template<int CTRL>
__device__ __forceinline__ float dpp_max(float x) {
  const int t = __builtin_amdgcn_update_dpp(0, __float_as_int(x), CTRL, 0xF, 0xF, true);
  return fmaxf(x, __int_as_float(t));
}
__device__ __forceinline__ float red16(float v) {   // sum over 16-lane row
  v = dpp_add<0xB1, 0xF>(v);
  v = dpp_add<0x4E, 0xF>(v);
  v = dpp_add<0x124, 0xF>(v);
  v = dpp_add<0x128, 0xF>(v);
  return v;
}
__device__ __forceinline__ float lane63f(float v) { // uniform broadcast of lane 63
  return __int_as_float(__builtin_amdgcn_readlane(__float_as_int(v), 63));
}

// h state: node-major, UNSWIZZLED, row stride 136 f16 (272 B).
#define HROW 136

// gather one MFMA B-fragment set (kk, q), scaled by sc (exp2 pre-scaling)
__device__ __forceinline__ f16x8 gatherB(const float* __restrict__ cW,
                                         int kk, int q, int wv, int quad, int l15,
                                         float sc) {
  const int col = (q * 8 + wv) * 16 + l15;
  const int kb  = kk * 32 + quad * 8;
  f16x8 v;
  #pragma unroll
  for (int j = 0; j < 8; ++j) v[j] = (f16)(cW[(kb + j) * 640 + col] * sc);
  return v;
}

// Dynamic-LDS partition (149.5 KiB total; 1 block/CU, 160 KiB available)
#define BLDS_OFF 0              // 12 B-frag sets: 12*512*16 = 98304
#define CS_OFF   98304          // c state f32: 65*132*4 = 34320
#define HS_OFF   132624         // h state f16: 65*136*2 = 17680
#define LGP_OFF  150304         // logit partials: 8*64*4 = 2048
#define PS_OFF   152352         // p: 64*4
#define CLS_OFF  152608         // copy_left: 64*4
#define CRS_OFF  152864         // copy_right: 64*4
#define DYN_LDS  153120

// ---- pyramid (+ fused z0): 512 threads, 64 blocks (1 per CU) ----
// R15: EXACT revert to the R4 pyramid (best measured: 325us dispatch /
// 434.3us total in R6). All four register-hoist probes (R6 +160, R9 +144,
// R13 +48, R14 +16) spilled — the 128 VGPR + ~128 AGPR budget is fully
// consumed by Breg[28]+acc+state. Do not add ANY sustained register state.
__global__ __launch_bounds__(512, 1) void pyramid_kernel(
    const int*   __restrict__ sentences,
    const float* __restrict__ emb,
    const float* __restrict__ cW,
    const float* __restrict__ cb, const float* __restrict__ selw, const float* __restrict__ selb,
    const float* __restrict__ w0, const float* __restrict__ b0,
    const float* __restrict__ cbias,
    f16* __restrict__ z0h, float* __restrict__ out)
{
  extern __shared__ __align__(16) char dyn[];
  f16x8* Blds = (f16x8*)(dyn + BLDS_OFF);
  float* cS   = (float*)(dyn + CS_OFF);
  f16*   hS   = (f16*)  (dyn + HS_OFF);
  float* lgp  = (float*)(dyn + LGP_OFF);
  float* pS   = (float*)(dyn + PS_OFF);
  float* clS  = (float*)(dyn + CLS_OFF);
  float* crS  = (float*)(dyn + CRS_OFF);

  const int tid  = threadIdx.x;
  const int b    = blockIdx.x;
  const int wv   = tid >> 6;
  const int lane = tid & 63;
  const int quad = lane >> 4;
  const int l15  = lane & 15;
  const int d    = wv * 16 + l15;

  // init logits with cbias (z1 kernel atomically accumulates onto this)
  if (b == 0 && tid < 192) out[tid] = cbias[tid % 3];

  // ---- B in LDS: s<4 -> (kk=4+s, q=3); s>=4 -> (kk=s-4, q=4) ----
  #pragma unroll
  for (int s = 0; s < 12; ++s) {
    const int kk = (s < 4) ? (4 + s) : (s - 4);
    const int q  = (s < 4) ? 3 : 4;
    const float sc = (q == 3) ? (2.0f * LOG2E) : LOG2E;
    Blds[s * 512 + tid] = gatherB(cW, kk, q, wv, quad, l15, sc);
  }
  // ---- persistent B in regs: q=0..2 all kk (24) + q=3,kk=0..3 (4) = 28 sets ----
  f16x8 Breg[28];
  #pragma unroll
  for (int kk = 0; kk < 8; ++kk)
    #pragma unroll
    for (int q = 0; q < 3; ++q)
      Breg[kk * 3 + q] = gatherB(cW, kk, q, wv, quad, l15, LOG2E);
  #pragma unroll
  for (int kk = 0; kk < 4; ++kk)
    Breg[24 + kk] = gatherB(cW, kk, 3, wv, quad, l15, 2.0f * LOG2E);

  // ---- embedding gather: h -> LDS f16, c -> LDS f32 ----
  {
    const int s = tid >> 3, part = tid & 7;
    const int row = sentences[b * SEQ + s];
    const float4* er = (const float4*)(emb + (size_t)row * 256 + part * 32);
    #pragma unroll
    for (int i4 = 0; i4 < 8; ++i4) {
      const float4 v = er[i4];
      const float vv[4] = {v.x, v.y, v.z, v.w};
      #pragma unroll
      for (int c = 0; c < 4; ++c) {
        const int f = part * 32 + i4 * 4 + c;
        if (f < 128) hS[s * HROW + f] = (f16)vv[c];
        else         cS[s * 132 + (f - 128)] = vv[c];
      }
    }
  }
  if (tid < HROW) hS[64 * HROW + tid] = (f16)0.f;   // guard row (node 64)
  if (tid < 132)  cS[64 * 132 + tid] = 0.f;
  __syncthreads();

  float bq[5];
  #pragma unroll
  for (int q = 0; q < 5; ++q)
    bq[q] = cb[q * 128 + d] * ((q == 3) ? (2.0f * LOG2E) : LOG2E);
  const float swh = selw[d], swc = selw[128 + d], selbv = selb[0];

  // ---- pyramid: 63 sequential layers; zero global memory in the loop ----
  for (int W = 63; W >= 1; --W) {
    const int NMT = (W + 15) >> 4;
    float chF[4][4], ccF[4][4], vF[4][4];

    // ---- phase A: MFMA + gate epilogue, one mt at a time (NO LDS writes) ----
    #pragma unroll
    for (int mt = 0; mt < 4; ++mt) if (mt < NMT) {
      f32x4 acc[5];
      #pragma unroll
      for (int q = 0; q < 5; ++q) acc[q] = (f32x4){bq[q], bq[q], bq[q], bq[q]};
      const int rb = (mt * 16 + l15) * HROW + quad * 8;   // layer-invariant base
      #pragma unroll
      for (int kk = 0; kk < 8; ++kk) {
        const f16x8 av = *(const f16x8*)&hS[rb + (kk >> 2) * HROW + (kk & 3) * 32];
        #pragma unroll
        for (int q = 0; q < 3; ++q)
          acc[q] = __builtin_amdgcn_mfma_f32_16x16x32_f16(av, Breg[kk * 3 + q], acc[q], 0, 0, 0);
        const f16x8 b3 = (kk < 4) ? Breg[24 + kk] : Blds[(kk - 4) * 512 + tid];
        acc[3] = __builtin_amdgcn_mfma_f32_16x16x32_f16(av, b3, acc[3], 0, 0, 0);
        const f16x8 b4 = Blds[(4 + kk) * 512 + tid];
        acc[4] = __builtin_amdgcn_mfma_f32_16x16x32_f16(av, b4, acc[4], 0, 0, 0);
      }
      const int n0q = mt * 16 + quad * 4;
      if (n0q < W) {                    // quad-uniform: whole dead quads skip
        float c5[5];
        #pragma unroll
        for (int r = 0; r < 5; ++r) c5[r] = cS[(n0q + r) * 132 + d];
        #pragma unroll
        for (int r = 0; r < 4; ++r) {
          const float c = sigp_(acc[1][r]) * c5[r] + sigp_(acc[2][r]) * c5[r + 1]
                        + sigp_(acc[0][r]) * tanhp_(acc[3][r]);
          const float h = sigp_(acc[4][r]) * tanh_(c);
          ccF[mt][r] = c; chF[mt][r] = h;
          vF[mt][r] = red16(__builtin_fmaf(h, swh, c * swc));   // logit partial
        }
      }
    }
    // ---- flush logit partials (single LDS-write block, after all reads) ----
    if (l15 == 0) {
      #pragma unroll
      for (int mt = 0; mt < 4; ++mt) if (mt < NMT) {
        const int n0q = mt * 16 + quad * 4;
        if (n0q < W) {
          #pragma unroll
          for (int r = 0; r < 4; ++r) {
            const int n = n0q + r;
            if (n < W) lgp[(wv << 6) + n] = vF[mt][r];
          }
        }
      }
    }
    __syncthreads();

    // ---- phase B: softmax + prefix sums, redundantly per wave ----
    {
      float lg = -3.0e38f;
      if (lane < W) {
        float s = selbv;
        #pragma unroll
        for (int dg = 0; dg < 8; ++dg) s += lgp[(dg << 6) + lane];
        lg = s;
      }
      // full-wave max: row butterfly then row_bcast chain; total lands in lane 63
      float m = lg;
      m = dpp_max<0xB1>(m); m = dpp_max<0x4E>(m);
      m = dpp_max<0x124>(m); m = dpp_max<0x128>(m);
      m = dpp_max<0x142>(m); m = dpp_max<0x143>(m);
      m = lane63f(m);
      const float e = (lane < W) ? __expf(lg - m) : 0.f;
      float t = e;
      t = dpp_add<0xB1, 0xF>(t); t = dpp_add<0x4E, 0xF>(t);
      t = dpp_add<0x124, 0xF>(t); t = dpp_add<0x128, 0xF>(t);
      t = dpp_add<0x142, 0xF>(t); t = dpp_add<0x143, 0xF>(t);
      t = lane63f(t);
      const float p = e * __builtin_amdgcn_rcpf(t);
      float cs = p;                       // inclusive scan (DPP)
      cs = dpp_add<0x111, 0xF>(cs);
      cs = dpp_add<0x112, 0xF>(cs);
      cs = dpp_add<0x114, 0xF>(cs);
      cs = dpp_add<0x118, 0xF>(cs);
      cs = dpp_add<0x142, 0xA>(cs);
      cs = dpp_add<0x143, 0xC>(cs);
      const float T = lane63f(cs);
      if (lane < W) {
        pS[lane]  = p;
        clS[lane] = T - cs;
        crS[lane] = cs - p;
      }
    }
    // (no barrier: each wave wrote its own redundant copy)

    // ---- phase C: blend; read-all-then-write-all per mt ----
    #pragma unroll
    for (int mt = 0; mt < 4; ++mt) if (mt < NMT) {
      const int n0q = mt * 16 + quad * 4;
      if (n0q < W) {                    // skip dead quads entirely
        const f32x4 pv  = *(const f32x4*)&pS[n0q];
        const f32x4 clv = *(const f32x4*)&clS[n0q];
        const f32x4 crv = *(const f32x4*)&crS[n0q];
        float oh[5], c5[5];
        #pragma unroll
        for (int r = 0; r < 5; ++r) {
          oh[r] = (float)hS[(n0q + r) * HROW + d];
          c5[r] = cS[(n0q + r) * 132 + d];
        }
        #pragma unroll
        for (int r = 0; r < 4; ++r) {
          const int n = n0q + r;
          if (n < W) {
            const float nh = clv[r] * oh[r] + crv[r] * oh[r + 1] + pv[r] * chF[mt][r];
            const float nc = clv[r] * c5[r] + crv[r] * c5[r + 1] + pv[r] * ccF[mt][r];
            hS[n * HROW + d] = (f16)nh;
            cS[n * 132 + d] = nc;
          }
        }
      }
    }
    __syncthreads();
  }

  // ---- fused z0: x = [h0||c0] (in LDS); each thread 2 cols; output f16 ----
  {
    const int c0 = 2 * tid;
    float a0 = 0.f, a1 = 0.f;
    #pragma unroll 8
    for (int k = 0; k < 128; ++k) {
      const float x  = (float)hS[k];                       // row 0, LDS broadcast
      const float2 w = *(const float2*)&w0[k * 1024 + c0]; // coalesced
      a0 = __builtin_fmaf(x, w.x, a0);
      a1 = __builtin_fmaf(x, w.y, a1);
    }
    #pragma unroll 8
    for (int k = 0; k < 128; ++k) {
      const float x  = cS[k];                              // LDS broadcast
      const float2 w = *(const float2*)&w0[(128 + k) * 1024 + c0];
      a0 = __builtin_fmaf(x, w.x, a0);
      a1 = __builtin_fmaf(x, w.y, a1);
    }
    f16x2 p;
    p[0] = (f16)fmaxf(a0 + b0[c0], 0.f);
    p[1] = (f16)fmaxf(a1 + b0[c0 + 1], 0.f);
    *(f16x2*)&z0h[b * 1024 + c0] = p;      // z0h[row=b][k], A-operand layout
  }
}

// ---- z1 + classifier, MFMA: 64 blocks x 256 thr (4 waves) ----
// Block = 16 cols of w1 (column-split => w1 read ONCE device-wide).
// R15: T14 async-STAGE split — chunk k+1's global loads (z0h 8xb128 + w1
// 4xfloat4 = 48 VGPRs) are issued into registers BEFORE chunk k's publish
// barrier, hiding ~900-cyc HBM latency under barrier + MFMA. LDS writes
// happen after the protect-barrier of the next iteration.
#define ZROW 264   // 256 + 8 f16 pad (4-bank row stride)
__global__ __launch_bounds__(256) void z1_kernel(
    const f16* __restrict__ z0h, const float* __restrict__ w1,
    const float* __restrict__ b1, const float* __restrict__ cwt,
    float* __restrict__ out)
{
  __shared__ __align__(16) f16 ZL[64 * ZROW];   // 33792 B
  __shared__ __align__(16) f16 WL[16 * ZROW];   // 8448 B
  const int t    = threadIdx.x;
  const int wv   = t >> 6;
  const int lane = t & 63;
  const int quad = lane >> 4;
  const int l15  = lane & 15;
  const int c0   = blockIdx.x * 16;

  f16x8 zr[8];    // prefetched z0h chunk (32 VGPRs)
  float4 wr[4];   // prefetched w1 chunk (16 VGPRs)

  // issue chunk 0's global loads immediately
  #pragma unroll
  for (int i = 0; i < 8; ++i) {
    const int idx8 = (t + i * 256) * 8;
    zr[i] = *(const f16x8*)&z0h[(idx8 >> 8) * 1024 + 0 + (idx8 & 255)];
  }
  #pragma unroll
  for (int i = 0; i < 4; ++i) {
    const int idx = i * 256 + t;
    wr[i] = *(const float4*)&w1[(size_t)(0 + (idx >> 2)) * 1024 + c0 + (idx & 3) * 4];
  }

  f32x4 acc = (f32x4){0.f, 0.f, 0.f, 0.f};
  #pragma unroll
  for (int ch = 0; ch < 4; ++ch) {
    const int k0n = (ch + 1) * 256;     // next chunk base (compile-time)
    if (ch) __syncthreads();            // protect previous chunk's LDS reads
    // write prefetched registers -> LDS
    #pragma unroll
    for (int i = 0; i < 8; ++i) {
      const int idx8 = (t + i * 256) * 8;
      *(f16x8*)&ZL[(idx8 >> 8) * ZROW + (idx8 & 255)] = zr[i];
    }
    #pragma unroll
    for (int i = 0; i < 4; ++i) {
      const int idx = i * 256 + t;
      const int kc  = idx >> 2;
      const int c4  = (idx & 3) * 4;
      WL[(c4 + 0) * ZROW + kc] = (f16)wr[i].x;
      WL[(c4 + 1) * ZROW + kc] = (f16)wr[i].y;
      WL[(c4 + 2) * ZROW + kc] = (f16)wr[i].z;
      WL[(c4 + 3) * ZROW + kc] = (f16)wr[i].w;
    }
    // prefetch next chunk into the (now free) registers — overlaps barrier+MFMA
    if (ch < 3) {
      #pragma unroll
      for (int i = 0; i < 8; ++i) {
        const int idx8 = (t + i * 256) * 8;
        zr[i] = *(const f16x8*)&z0h[(idx8 >> 8) * 1024 + k0n + (idx8 & 255)];
      }
      #pragma unroll
      for (int i = 0; i < 4; ++i) {
        const int idx = i * 256 + t;
        wr[i] = *(const float4*)&w1[(size_t)(k0n + (idx >> 2)) * 1024 + c0 + (idx & 3) * 4];
      }
    }
    __syncthreads();                    // publish LDS
    #pragma unroll
    for (int kk = 0; kk < 8; ++kk) {
      const f16x8 av = *(const f16x8*)&ZL[(wv * 16 + l15) * ZROW + kk * 32 + quad * 8];
      const f16x8 bv = *(const f16x8*)&WL[l15 * ZROW + kk * 32 + quad * 8];
      acc = __builtin_amdgcn_mfma_f32_16x16x32_f16(av, bv, acc, 0, 0, 0);
    }
  }

  // epilogue: z1 = relu(acc + b1); classifier partials over this block's 16 cols
  const int col = c0 + l15;
  const float bias = b1[col];
  const float cw0 = cwt[col * 3], cw1 = cwt[col * 3 + 1], cw2 = cwt[col * 3 + 2];
  #pragma unroll
  for (int r = 0; r < 4; ++r) {
    const int row = wv * 16 + quad * 4 + r;
    const float z = fmaxf(acc[r] + bias, 0.f);
    const float p0 = red16(z * cw0);
    const float p1 = red16(z * cw1);
    const float p2 = red16(z * cw2);
    if (l15 == 0) {
      atomicAdd(&out[row * 3 + 0], p0);
      atomicAdd(&out[row * 3 + 1], p1);
      atomicAdd(&out[row * 3 + 2], p2);
    }
  }
}

extern "C" void kernel_launch(void* const* d_in, const int* in_sizes, int n_in,
                              void* d_out, int out_size, void* d_ws, size_t ws_size,
                              hipStream_t stream) {
  (void)in_sizes; (void)n_in; (void)out_size; (void)ws_size;
  f16* z0h = (f16*)d_ws;                                 // 64*1024*2 = 131072 B

  // allow >64 KB dynamic LDS (160 KiB/CU on gfx950); host-state call, not enqueued
  (void)hipFuncSetAttribute((const void*)pyramid_kernel,
                            hipFuncAttributeMaxDynamicSharedMemorySize, DYN_LDS);

  pyramid_kernel<<<dim3(64), dim3(512), DYN_LDS, stream>>>(
      (const int*)d_in[0],          // sentences
      (const float*)d_in[2],        // emb
      (const float*)d_in[3],        // comp_W (self-gathered to fragments)
      (const float*)d_in[4],        // comp_b
      (const float*)d_in[5],        // sel_w
      (const float*)d_in[6],        // sel_b
      (const float*)d_in[7],        // mlp_w0
      (const float*)d_in[8],        // mlp_b0
      (const float*)d_in[12],       // cls_b (out init)
      z0h, (float*)d_out);
  z1_kernel<<<dim3(64), dim3(256), 0, stream>>>(
      z0h,
      (const float*)d_in[9],        // mlp_w1
      (const float*)d_in[10],       // mlp_b1
      (const float*)d_in[11],       // cls_w
      (float*)d_out);
}